// Round 14
// baseline (226.316 us; speedup 1.0000x reference)
//
#include <hip/hip_runtime.h>
#include <hip/hip_bf16.h>
#include <math.h>

#define HIDDEN 100

typedef __attribute__((ext_vector_type(8))) short bf16x8;
typedef __attribute__((ext_vector_type(4))) float f32x4;

__device__ inline unsigned short f2bf(float v) {
    union { float f; unsigned u; } x; x.f = v;
    unsigned r = x.u + 0x7fff + ((x.u >> 16) & 1);   // RNE
    return (unsigned short)(r >> 16);
}

constexpr int NPTS  = 25000;
constexpr int KPAIR = 8000;
constexpr int NC    = 28;
constexpr int CHUNK = 896;          // multiple of 64; 28*896 = 25088
constexpr int NPAD  = NC * CHUNK;   // padded target-panel rows (25088)
constexpr int HS    = 136;          // LDS H-slab stride (shorts) for mlp
constexpr int NB_SUP = 2000;
constexpr int GM     = (NPTS + 31) / 32;   // 782 mlp blocks per dir
constexpr int NB_MLP = 2 * GM;
constexpr int PREP_B8 = (2 * NPAD) / 8;    // 6272 row-prep blocks (8 rows each)

// ---------------------------------------------------------------------------
// Weight panels -> fragment-ordered bf16, zero-padded. 29 blocks x 256.
// ---------------------------------------------------------------------------
__global__ __launch_bounds__(256) void w_prep(
    const float* __restrict__ W1, unsigned short* __restrict__ P1,
    const float* __restrict__ W2, unsigned short* __restrict__ P2,
    const float* __restrict__ W3, unsigned short* __restrict__ P3,
    const float* __restrict__ W4, unsigned short* __restrict__ P4)
{
    const int ln = threadIdx.x & 63;
    int b = blockIdx.x * 4 + (threadIdx.x >> 6);
    if (b >= 116) return;
    const float* W; unsigned short* P; int DK, DN, NT;
    if (b < 28)      {          W = W1; P = P1; DK = 100; DN = 100; NT = 7; }
    else if (b < 60) { b -= 28; W = W2; P = P2; DK = 100; DN = 120; NT = 8; }
    else if (b < 88) { b -= 60; W = W3; P = P3; DK = 120; DN = 100; NT = 7; }
    else             { b -= 88; W = W4; P = P4; DK = 100; DN = 100; NT = 7; }
    const int kt = b / NT, nt = b - kt * NT;
    const int n  = nt * 16 + (ln & 15);
    const int k0 = kt * 32 + (ln >> 4) * 8;
    unsigned short* dst = P + ((size_t)(kt * NT + nt) * 64 + ln) * 8;
    #pragma unroll
    for (int j = 0; j < 8; j++) {
        const int k = k0 + j;
        const float f = (k < DK && n < DN) ? W[k * DN + n] : 0.f;
        dst[j] = f2bf(f);
    }
}

// ---------------------------------------------------------------------------
// MFMA stage helpers (16x16x32 layouts HW-verified: absmax 0.0 R2-R13).
// ---------------------------------------------------------------------------
template<int NT>
__device__ inline void run_stage(const bf16x8 af[4], const unsigned short* __restrict__ WP,
                                 int ln, f32x4 acc[NT])
{
    #pragma unroll
    for (int nt = 0; nt < NT; nt++) acc[nt] = (f32x4){0.f, 0.f, 0.f, 0.f};
    #pragma unroll
    for (int kt = 0; kt < 4; kt++) {
        #pragma unroll
        for (int nt = 0; nt < NT; nt++) {
            const bf16x8 wf = *reinterpret_cast<const bf16x8*>(WP + ((size_t)(kt * NT + nt) * 64 + ln) * 8);
            acc[nt] = __builtin_amdgcn_mfma_f32_16x16x32_bf16(af[kt], wf, acc[nt], 0, 0, 0);
        }
    }
}

template<int NT, int DN, bool RELU>
__device__ inline void pack_h(const f32x4 acc[NT], const float* __restrict__ B,
                              unsigned short* __restrict__ Hs, int col, int quad)
{
    #pragma unroll
    for (int nt = 0; nt < NT; nt++) {
        const int n = nt * 16 + col;
        const float b = (n < DN) ? B[n] : 0.f;
        #pragma unroll
        for (int r = 0; r < 4; r++) {
            float v = acc[nt][r] + b;
            if (RELU) v = fmaxf(v, 0.f);
            Hs[(quad * 4 + r) * HS + n] = f2bf(v);
        }
    }
}

template<int NT, int DN>
__device__ inline void store_pack(const f32x4 acc[NT], const float* __restrict__ B,
                                  float* __restrict__ Y, unsigned short* __restrict__ Hs,
                                  int rowbase, int col, int quad, int N)
{
    #pragma unroll
    for (int nt = 0; nt < NT; nt++) {
        const int n = nt * 16 + col;
        const float b = (n < DN) ? B[n] : 0.f;
        #pragma unroll
        for (int r = 0; r < 4; r++) {
            const float v = acc[nt][r] + b;
            const int row = rowbase + quad * 4 + r;
            if (n < DN && row < N) Y[(size_t)row * DN + n] = v;
            Hs[(quad * 4 + r) * HS + n] = f2bf(v);
        }
    }
}

__device__ inline void load_haf(const unsigned short* __restrict__ Hs, int col, int quad,
                                bf16x8 af[4])
{
    const unsigned short* p = Hs + col * HS + quad * 8;
    #pragma unroll
    for (int kt = 0; kt < 4; kt++)
        af[kt] = *reinterpret_cast<const bf16x8*>(p + kt * 32);
}

// Direct fp32 -> A-frag load with in-register bf16 conversion. Exactness:
// groups fully below DIN load exactly; groups fully >= DIN hit zero weights
// (clamped address, garbage values harmless); DIN=100's straddling group
// (base 96) loads float4 (k=96..99 exact) + zeros for dead k=100..103.
template<int DIN>
__device__ inline void load_a_direct(const float* __restrict__ X, int r, int quad,
                                     bf16x8 af[4])
{
    const float* ap = X + (size_t)r * DIN;
    #pragma unroll
    for (int kt = 0; kt < 4; kt++) {
        const int base = kt * 32 + quad * 8;
        float4 v0, v1;
        if (DIN == 100) {
            if (base == 96) {
                v0 = *reinterpret_cast<const float4*>(ap + 96);
                v1 = make_float4(0.f, 0.f, 0.f, 0.f);
            } else {
                const int b = (base < 92) ? base : 92;
                v0 = *reinterpret_cast<const float4*>(ap + b);
                v1 = *reinterpret_cast<const float4*>(ap + b + 4);
            }
        } else {
            const int b = (base < 112) ? base : 112;
            v0 = *reinterpret_cast<const float4*>(ap + b);
            v1 = *reinterpret_cast<const float4*>(ap + b + 4);
        }
        bf16x8 f;
        f[0] = (short)f2bf(v0.x); f[1] = (short)f2bf(v0.y);
        f[2] = (short)f2bf(v0.z); f[3] = (short)f2bf(v0.w);
        f[4] = (short)f2bf(v1.x); f[5] = (short)f2bf(v1.y);
        f[6] = (short)f2bf(v1.z); f[7] = (short)f2bf(v1.w);
        af[kt] = f;
    }
}

template<int NT, int DN>
__device__ inline float norm_stage(const f32x4 acc[NT], const float* __restrict__ B,
                                   const float* __restrict__ REF,
                                   int rowbase, int col, int quad, int N)
{
    float ra[4] = {0.f, 0.f, 0.f, 0.f};
    #pragma unroll
    for (int nt = 0; nt < NT; nt++) {
        const int n = nt * 16 + col;
        if (n < DN) {
            const float b = B[n];
            #pragma unroll
            for (int r = 0; r < 4; r++) {
                const int row = rowbase + quad * 4 + r;
                if (row < N) {
                    const float d = acc[nt][r] + b - REF[(size_t)row * DN + n];
                    ra[r] = fmaf(d, d, ra[r]);
                }
            }
        }
    }
    #pragma unroll
    for (int o = 1; o < 16; o <<= 1) {
        #pragma unroll
        for (int r = 0; r < 4; r++) ra[r] += __shfl_xor(ra[r], o);
    }
    float s = 0.f;
    if (col == 0) {
        #pragma unroll
        for (int r = 0; r < 4; r++)
            if (rowbase + quad * 4 + r < N) s += sqrtf(ra[r]);
    }
    return s;
}

// ---------------------------------------------------------------------------
// Fused 4-stage MLP chain body (A loaded directly from fp32 input).
// ---------------------------------------------------------------------------
template<int DIN, int DMID, int NT2, int NTF>
__device__ __forceinline__ void mlp_chain(
    int bid,
    const float* __restrict__ XREF,
    const unsigned short* __restrict__ WP1, const float* __restrict__ B1,
    const unsigned short* __restrict__ WP2, const float* __restrict__ B2,
    const unsigned short* __restrict__ WP3, const float* __restrict__ B3,
    const unsigned short* __restrict__ WP4, const float* __restrict__ B4,
    float* __restrict__ Y, float* __restrict__ part, int N,
    unsigned short (*H)[16 * HS], float* bred)
{
    const int tid = threadIdx.x;
    const int wv = tid >> 6, ln = tid & 63;
    const int col = ln & 15, quad = ln >> 4;
    const int rowbase = bid * 32 + wv * 16;

    {
        unsigned* Hz = reinterpret_cast<unsigned*>(H[wv]);
        for (int i = ln; i < 16 * HS / 2; i += 64) Hz[i] = 0u;
    }

    bf16x8 af[4];
    load_a_direct<DIN>(XREF, min(rowbase + col, N - 1), quad, af);

    f32x4 accA[7];
    run_stage<7>(af, WP1, ln, accA);
    pack_h<7, HIDDEN, true>(accA, B1, H[wv], col, quad);
    load_haf(H[wv], col, quad, af);

    f32x4 accB[NT2];
    run_stage<NT2>(af, WP2, ln, accB);
    store_pack<NT2, DMID>(accB, B2, Y, H[wv], rowbase, col, quad, N);
    load_haf(H[wv], col, quad, af);

    run_stage<7>(af, WP3, ln, accA);
    pack_h<7, HIDDEN, true>(accA, B3, H[wv], col, quad);
    load_haf(H[wv], col, quad, af);

    f32x4 accC[NTF];
    run_stage<NTF>(af, WP4, ln, accC);
    const float s = norm_stage<NTF, DIN>(accC, B4, XREF, rowbase, col, quad, N);

    if (col == 0) bred[wv * 4 + quad] = s;
    __syncthreads();
    if (tid == 0) {
        float t = 0.f;
        #pragma unroll
        for (int i = 0; i < 8; i++) t += bred[i];
        part[bid] = t;
    }
}

// ---------------------------------------------------------------------------
// One dispatch: MLP chains (blocks [0, 2GM)) + row-panel prep (the rest).
// Chains read fp32 inputs directly (no dependency on panel prep); the
// latency-bound prep blocks fill the chains' dependency stalls.
// ---------------------------------------------------------------------------
__global__ __launch_bounds__(128) void mlp_prep(
    const float* __restrict__ xw, const float* __restrict__ yw,
    unsigned short* __restrict__ ybf, unsigned short* __restrict__ xbf,
    const unsigned short* __restrict__ wp_fx1, const float* __restrict__ fx_b1,
    const unsigned short* __restrict__ wp_fx2, const float* __restrict__ fx_b2,
    const unsigned short* __restrict__ wp_gy1, const float* __restrict__ gy_b1,
    const unsigned short* __restrict__ wp_gy2, const float* __restrict__ gy_b2,
    float* __restrict__ xm, float* __restrict__ ym,
    float* __restrict__ part, int N)
{
    __shared__ unsigned short H[2][16 * HS];
    __shared__ float bred[8];

    if (blockIdx.x < GM) {
        mlp_chain<100, 120, 8, 7>(blockIdx.x, xw,
            wp_fx1, fx_b1, wp_fx2, fx_b2, wp_gy1, gy_b1, wp_gy2, gy_b2,
            xm, part, N, H, bred);
        return;
    }
    if (blockIdx.x < 2 * GM) {
        mlp_chain<120, 100, 7, 8>(blockIdx.x - GM, yw,
            wp_gy1, gy_b1, wp_gy2, gy_b2, wp_fx1, fx_b1, wp_fx2, fx_b2,
            ym, part + GM, N, H, bred);
        return;
    }

    // ---- row-panel prep: 8 rows/block (2 waves x 4 rows) ----
    const int bid = blockIdx.x - 2 * GM;
    const int wv = threadIdx.x >> 6, ln = threadIdx.x & 63;
    #pragma unroll
    for (int i = 0; i < 4; i++) {
        const int gw = bid * 8 + wv * 4 + i;
        const int isY = (gw < NPAD);
        const int r = isY ? gw : gw - NPAD;
        const int D = isY ? 120 : 100;
        unsigned short* dst = (isY ? ybf : xbf) + (size_t)r * 128;
        if (r < N) {
            const float* src = (isY ? yw : xw) + (size_t)r * D;
            const float v0 = (ln < D) ? src[ln] : 0.f;
            const float v1 = (ln + 64 < D) ? src[ln + 64] : 0.f;
            float s = fmaf(v0, v0, v1 * v1);
            #pragma unroll
            for (int o = 1; o < 64; o <<= 1) s += __shfl_xor(s, o);
            dst[ln] = f2bf(v0);
            dst[ln + 64] = (ln == 63) ? f2bf(s) : f2bf(v1);
        } else {
            dst[ln] = 0;
            dst[ln + 64] = (ln == 63) ? f2bf(1e30f) : (unsigned short)0;
        }
    }
}

// ---------------------------------------------------------------------------
// sup + gather fused: wave per pair; also emits -2-scaled bf16 query panels.
// ---------------------------------------------------------------------------
__global__ __launch_bounds__(256) void sup_gather(
    const float* __restrict__ xm, const float* __restrict__ ym,
    const float* __restrict__ xw, const float* __restrict__ yw,
    const int* __restrict__ im, int K, float* __restrict__ part,
    unsigned short* __restrict__ axf, unsigned short* __restrict__ ayf)
{
    const int gw = (int)((blockIdx.x * 256 + threadIdx.x) >> 6);
    const int ln = threadIdx.x & 63;
    const int wv = threadIdx.x >> 6;
    float cnt = 0.f;
    if (gw < K) {
        const int xi = im[2 * gw], yi = im[2 * gw + 1];
        const float* a = xm + (size_t)xi * 120;
        const float* b = yw + (size_t)yi * 120;
        const float a0 = a[ln];
        const float a1 = (ln + 64 < 120) ? a[ln + 64] : 0.f;
        float s1 = 0.f;
        { const float d0 = a0 - b[ln]; s1 = d0 * d0; }
        if (ln + 64 < 120) { const float d1 = a1 - b[ln + 64]; s1 = fmaf(d1, d1, s1); }
        unsigned short* pax = axf + (size_t)gw * 128;
        pax[ln] = f2bf(-2.f * a0);
        pax[ln + 64] = (ln == 63) ? f2bf(1.f) : ((ln + 64 < 120) ? f2bf(-2.f * a1) : (unsigned short)0);

        const float* c = ym + (size_t)yi * 100;
        const float* e = xw + (size_t)xi * 100;
        const float c0 = c[ln];
        const float c1 = (ln + 64 < 100) ? c[ln + 64] : 0.f;
        float s2 = 0.f;
        { const float d0 = c0 - e[ln]; s2 = d0 * d0; }
        if (ln + 64 < 100) { const float d1 = c1 - e[ln + 64]; s2 = fmaf(d1, d1, s2); }
        unsigned short* pay = ayf + (size_t)gw * 128;
        pay[ln] = f2bf(-2.f * c0);
        pay[ln + 64] = (ln == 63) ? f2bf(1.f) : ((ln + 64 < 100) ? f2bf(-2.f * c1) : (unsigned short)0);

        #pragma unroll
        for (int o = 32; o > 0; o >>= 1) { s1 += __shfl_down(s1, o); s2 += __shfl_down(s2, o); }
        if (ln == 0) cnt = sqrtf(s1) + sqrtf(s2);
    }
    __shared__ float wsum[4];
    if (ln == 0) wsum[wv] = cnt;
    __syncthreads();
    if (threadIdx.x == 0)
        part[blockIdx.x] = wsum[0] + wsum[1] + wsum[2] + wsum[3];
}

// ---------------------------------------------------------------------------
// 16B global->LDS DMA for one 32x128 bf16 tile (8 KB), XOR-swizzled.
// ---------------------------------------------------------------------------
__device__ inline void stage32(const unsigned short* __restrict__ T, int jbase,
                               unsigned char* dst0, int wv, int ln)
{
    #pragma unroll
    for (int h = 0; h < 2; h++) {
        const int c = h * 256 + wv * 64 + ln;
        const int r = c >> 4;
        const int gc = (c & 15) ^ (r & 15);
        const unsigned short* g = T + ((size_t)(jbase + r) << 7) + gc * 8;
        unsigned char* l = dst0 + h * 4096 + wv * 1024;
        __builtin_amdgcn_global_load_lds(
            (const __attribute__((address_space(1))) void*)g,
            (__attribute__((address_space(3))) void*)l, 16, 0, 0);
    }
}

// ---------------------------------------------------------------------------
// MFMA 1-NN (R11/R13 best: 16x16x32, 256-row blocks, 64-row double-step,
// DMA staging, XOR swizzle, mantissa-packed j>>4 argmin). (256,3): the only
// empirically no-spill bound (R6/R7/R12 spill history).
// ---------------------------------------------------------------------------
__global__ __launch_bounds__(256, 3) void nn_mfma(
    const unsigned short* __restrict__ A0, const unsigned short* __restrict__ T0,
    float* __restrict__ pm0, int* __restrict__ pi0,
    const unsigned short* __restrict__ A1, const unsigned short* __restrict__ T1,
    float* __restrict__ pm1, int* __restrict__ pi1,
    int K)
{
    __shared__ __align__(16) unsigned char smem[32768];
    float (*rm)[64][17] = reinterpret_cast<float(*)[64][17]>(smem);

    const unsigned short* A = blockIdx.z ? A1 : A0;
    const unsigned short* T = blockIdx.z ? T1 : T0;
    float* pmin = blockIdx.z ? pm1 : pm0;
    int*   pidx = blockIdx.z ? pi1 : pi0;

    const int tid = threadIdx.x;
    const int wv = tid >> 6, ln = tid & 63;
    const int col = ln & 15, quad = ln >> 4;
    const int k0 = blockIdx.x * 256;
    const int jstart = blockIdx.y * CHUNK;
    constexpr int NSTEPS = CHUNK / 64;   // 14

    bf16x8 afrag[4][4];
    #pragma unroll
    for (int t = 0; t < 4; t++) {
        const int ar = min(k0 + wv * 64 + t * 16 + col, K - 1);
        const unsigned short* ab = A + (size_t)ar * 128 + quad * 8;
        #pragma unroll
        for (int s = 0; s < 4; s++)
            afrag[t][s] = *reinterpret_cast<const bf16x8*>(ab + s * 32);
    }

    float m[4][4];
    #pragma unroll
    for (int t = 0; t < 4; t++)
        #pragma unroll
        for (int r = 0; r < 4; r++) m[t][r] = __builtin_inff();

    stage32(T, jstart,      smem,        wv, ln);
    stage32(T, jstart + 32, smem + 8192, wv, ln);
    __syncthreads();

    for (int ti = 0; ti < NSTEPS; ti++) {
        const int cur = ti & 1;
        if (ti + 1 < NSTEPS) {
            const int jn = jstart + (ti + 1) * 64;
            stage32(T, jn,      smem + (cur ^ 1) * 16384,        wv, ln);
            stage32(T, jn + 32, smem + (cur ^ 1) * 16384 + 8192, wv, ln);
        }

        #pragma unroll
        for (int h = 0; h < 2; h++) {
            const unsigned short* base = (const unsigned short*)(smem + cur * 16384 + h * 8192);
            const unsigned lowbase = (unsigned)((jstart + ti * 64 + h * 32) >> 4);
            #pragma unroll
            for (int sub = 0; sub < 2; sub++) {
                bf16x8 bfr[4];
                const int rr = sub * 16 + col;
                #pragma unroll
                for (int s = 0; s < 4; s++) {
                    const int ch = rr * 16 + ((quad + s * 4) ^ col);
                    bfr[s] = *reinterpret_cast<const bf16x8*>(base + ch * 8);
                }
                const unsigned low = lowbase + sub;
                #pragma unroll
                for (int t = 0; t < 4; t++) {
                    f32x4 acc = {0.f, 0.f, 0.f, 0.f};
                    #pragma unroll
                    for (int s = 0; s < 4; s++)
                        acc = __builtin_amdgcn_mfma_f32_16x16x32_bf16(afrag[t][s], bfr[s], acc, 0, 0, 0);
                    #pragma unroll
                    for (int r = 0; r < 4; r++) {
                        const unsigned u = (__float_as_uint(acc[r]) & 0xFFFFF800u) | low;
                        m[t][r] = fminf(m[t][r], __uint_as_float(u));
                    }
                }
            }
        }
        __syncthreads();
    }

    #pragma unroll
    for (int t = 0; t < 4; t++)
        #pragma unroll
        for (int r = 0; r < 4; r++)
            rm[wv][t * 16 + quad * 4 + r][col] = m[t][r];
    __syncthreads();

    const int k = k0 + tid;
    if (k < K) {
        const int w = tid >> 6, rr = tid & 63;
        float best = rm[w][rr][0];
        int bc = 0;
        #pragma unroll
        for (int c = 1; c < 16; c++) {
            const float v = rm[w][rr][c];
            if (v < best) { best = v; bc = c; }
        }
        const int j = (int)(((__float_as_uint(best) & 0x7FFu) << 4) | (unsigned)bc);
        pmin[(size_t)k * NC + blockIdx.y] = best;
        pidx[(size_t)k * NC + blockIdx.y] = j;
    }
}

// ---------------------------------------------------------------------------
// finish_all: mismatch indicators + sup partials + mlp partials. 64 atomics.
// ---------------------------------------------------------------------------
__global__ __launch_bounds__(256) void finish_all(
    const int* __restrict__ im,
    const float* __restrict__ pm0, const int* __restrict__ pi0,
    const float* __restrict__ pm1, const int* __restrict__ pi1,
    const float* __restrict__ part_sup, const float* __restrict__ part_mlp,
    int K, float* __restrict__ out, float inv_k, float inv_n)
{
    const int gid = blockIdx.x * 256 + threadIdx.x;
    const int stride = gridDim.x * 256;
    float local = 0.f;

    for (int p = gid; p < 2 * K; p += stride) {
        const int dir = (p >= K);
        const int kk = dir ? p - K : p;
        const float* pm = dir ? pm1 : pm0;
        const int*   pi = dir ? pi1 : pi0;
        float best = __builtin_inff();
        int bi = 0x7fffffff;
        #pragma unroll
        for (int c = 0; c < NC; c++) {
            const float v = pm[(size_t)kk * NC + c];
            const int  ii = pi[(size_t)kk * NC + c];
            if (v < best || (v == best && ii < bi)) { best = v; bi = ii; }
        }
        if (bi != im[2 * kk + dir]) local += inv_k;
    }
    for (int i = gid; i < NB_SUP; i += stride) local += part_sup[i] * inv_k;
    for (int i = gid; i < NB_MLP; i += stride) local += part_mlp[i] * inv_n;

    #pragma unroll
    for (int o = 32; o > 0; o >>= 1) local += __shfl_down(local, o);
    __shared__ float wsum[4];
    if ((threadIdx.x & 63) == 0) wsum[threadIdx.x >> 6] = local;
    __syncthreads();
    if (threadIdx.x == 0) {
        const float t = wsum[0] + wsum[1] + wsum[2] + wsum[3];
        if (t != 0.f) atomicAdd(out, t);
    }
}

// ---------------------------------------------------------------------------
extern "C" void kernel_launch(void* const* d_in, const int* in_sizes, int n_in,
                              void* d_out, int out_size, void* d_ws, size_t ws_size,
                              hipStream_t stream)
{
    const float* xw    = (const float*)d_in[0];
    const float* yw    = (const float*)d_in[1];
    const float* fx_w1 = (const float*)d_in[2];
    const float* fx_b1 = (const float*)d_in[3];
    const float* fx_w2 = (const float*)d_in[4];
    const float* fx_b2 = (const float*)d_in[5];
    const float* gy_w1 = (const float*)d_in[6];
    const float* gy_b1 = (const float*)d_in[7];
    const float* gy_w2 = (const float*)d_in[8];
    const float* gy_b2 = (const float*)d_in[9];
    const int*   imap  = (const int*)d_in[10];
    float* out = (float*)d_out;
    float* ws  = (float*)d_ws;

    constexpr int N = NPTS, K = KPAIR;

    float* xm      = ws;                           // N*120
    float* ym      = xm + (size_t)N * 120;         // N*100
    float* pmin_fx = ym + (size_t)N * 100;         // K*NC
    int*   pidx_fx = (int*)(pmin_fx + (size_t)K * NC);
    float* pmin_gy = (float*)(pidx_fx + (size_t)K * NC);
    int*   pidx_gy = (int*)(pmin_gy + (size_t)K * NC);
    unsigned short* ybf = (unsigned short*)(pidx_gy + (size_t)K * NC); // NPAD*128
    unsigned short* xbf = ybf + (size_t)NPAD * 128;                    // NPAD*128
    unsigned short* axf = xbf + (size_t)NPAD * 128;  // K*128
    unsigned short* ayf = axf + (size_t)K * 128;
    unsigned short* wp_fx1 = ayf + (size_t)K * 128;  // 28*512
    unsigned short* wp_fx2 = wp_fx1 + 28 * 512;      // 32*512
    unsigned short* wp_gy1 = wp_fx2 + 32 * 512;      // 28*512
    unsigned short* wp_gy2 = wp_gy1 + 28 * 512;      // 28*512
    float* part_sup = (float*)(wp_gy2 + 28 * 512);   // NB_SUP
    float* part_mlp = part_sup + NB_SUP;             // NB_MLP

    hipMemsetAsync(d_out, 0, sizeof(float), stream);

    w_prep<<<29, 256, 0, stream>>>(fx_w1, wp_fx1, fx_w2, wp_fx2,
                                   gy_w1, wp_gy1, gy_w2, wp_gy2);

    mlp_prep<<<2 * GM + PREP_B8, 128, 0, stream>>>(
        xw, yw, ybf, xbf,
        wp_fx1, fx_b1, wp_fx2, fx_b2, wp_gy1, gy_b1, wp_gy2, gy_b2,
        xm, ym, part_mlp, N);

    sup_gather<<<NB_SUP, 256, 0, stream>>>(xm, ym, xw, yw, imap, K, part_sup, axf, ayf);

    dim3 g1((K + 255) / 256, NC, 2);
    nn_mfma<<<g1, 256, 0, stream>>>(axf, ybf, pmin_fx, pidx_fx,
                                    ayf, xbf, pmin_gy, pidx_gy, K);

    finish_all<<<64, 256, 0, stream>>>(
        imap, pmin_fx, pidx_fx, pmin_gy, pidx_gy, part_sup, part_mlp,
        K, out, 1.f / K, 1.f / N);
}

// Round 15
// 218.119 us; speedup vs baseline: 1.0376x; 1.0376x over previous
//
#include <hip/hip_runtime.h>
#include <hip/hip_bf16.h>
#include <math.h>

#define HIDDEN 100

typedef __attribute__((ext_vector_type(8))) short bf16x8;
typedef __attribute__((ext_vector_type(4))) float f32x4;

__device__ inline unsigned short f2bf(float v) {
    union { float f; unsigned u; } x; x.f = v;
    unsigned r = x.u + 0x7fff + ((x.u >> 16) & 1);   // RNE
    return (unsigned short)(r >> 16);
}

// Force a wave-uniform value into a VGPR so (x & vmask) | vlow can fold into
// a single v_and_or_b32 (VOP3 disallows literals and >1 SGPR read).
__device__ inline unsigned vmov(unsigned s) {
    unsigned v;
    asm volatile("v_mov_b32 %0, %1" : "=v"(v) : "s"(s));
    return v;
}

constexpr int NPTS  = 25000;
constexpr int KPAIR = 8000;
constexpr int NC    = 28;
constexpr int CHUNK = 896;          // multiple of 64; 28*896 = 25088
constexpr int NPAD  = NC * CHUNK;   // padded target-panel rows (25088)
constexpr int HS    = 136;          // LDS H-slab stride (shorts) for mlp
constexpr int NB_SUP = 2000;
constexpr int GM     = (NPTS + 31) / 32;   // 782 mlp blocks per dir
constexpr int NB_MLP = 2 * GM;
constexpr int PREP_B = (2 * NPAD) / 16;    // 3136 row-prep blocks (16 rows each)

// ---------------------------------------------------------------------------
// prep: 16 rows/block (wave handles 4): bf16x128 padded row, col127=|row|^2,
// tn dropped (unused). Pad rows: zeros + col127=1e30. Tail: weight panels.
// ---------------------------------------------------------------------------
__global__ __launch_bounds__(256) void prep_kernel(
    const float* __restrict__ YW, unsigned short* __restrict__ ybf,
    const float* __restrict__ XW, unsigned short* __restrict__ xbf,
    const float* __restrict__ W1, unsigned short* __restrict__ P1,
    const float* __restrict__ W2, unsigned short* __restrict__ P2,
    const float* __restrict__ W3, unsigned short* __restrict__ P3,
    const float* __restrict__ W4, unsigned short* __restrict__ P4,
    int N)
{
    const int ln = threadIdx.x & 63;
    if (blockIdx.x < PREP_B) {
        const int g0 = blockIdx.x * 16 + (threadIdx.x >> 6) * 4;
        #pragma unroll
        for (int i = 0; i < 4; i++) {
            const int gw = g0 + i;
            const int isY = (gw < NPAD);
            const int r = isY ? gw : gw - NPAD;
            const int D = isY ? 120 : 100;
            unsigned short* dst = (isY ? ybf : xbf) + (size_t)r * 128;
            if (r < N) {
                const float* src = (isY ? YW : XW) + (size_t)r * D;
                const float v0 = (ln < D) ? src[ln] : 0.f;
                const float v1 = (ln + 64 < D) ? src[ln + 64] : 0.f;
                float s = fmaf(v0, v0, v1 * v1);
                #pragma unroll
                for (int o = 1; o < 64; o <<= 1) s += __shfl_xor(s, o);
                dst[ln] = f2bf(v0);
                dst[ln + 64] = (ln == 63) ? f2bf(s) : f2bf(v1);
            } else {
                dst[ln] = 0;
                dst[ln + 64] = (ln == 63) ? f2bf(1e30f) : (unsigned short)0;
            }
        }
        return;
    }
    // ---- weight panel prep ----
    int b = (blockIdx.x - PREP_B) * 4 + (threadIdx.x >> 6);
    if (b >= 116) return;
    const float* W; unsigned short* P; int DK, DN, NT;
    if (b < 28)      {          W = W1; P = P1; DK = 100; DN = 100; NT = 7; }
    else if (b < 60) { b -= 28; W = W2; P = P2; DK = 100; DN = 120; NT = 8; }
    else if (b < 88) { b -= 60; W = W3; P = P3; DK = 120; DN = 100; NT = 7; }
    else             { b -= 88; W = W4; P = P4; DK = 100; DN = 100; NT = 7; }
    const int kt = b / NT, nt = b - kt * NT;
    const int n  = nt * 16 + (ln & 15);
    const int k0 = kt * 32 + (ln >> 4) * 8;
    unsigned short* dst = P + ((size_t)(kt * NT + nt) * 64 + ln) * 8;
    #pragma unroll
    for (int j = 0; j < 8; j++) {
        const int k = k0 + j;
        const float f = (k < DK && n < DN) ? W[k * DN + n] : 0.f;
        dst[j] = f2bf(f);
    }
}

// ---------------------------------------------------------------------------
// MFMA stage helpers (16x16x32 layouts HW-verified: absmax 0.0 R2-R14).
// ---------------------------------------------------------------------------
template<int NT>
__device__ inline void run_stage(const bf16x8 af[4], const unsigned short* __restrict__ WP,
                                 int ln, f32x4 acc[NT])
{
    #pragma unroll
    for (int nt = 0; nt < NT; nt++) acc[nt] = (f32x4){0.f, 0.f, 0.f, 0.f};
    #pragma unroll
    for (int kt = 0; kt < 4; kt++) {
        #pragma unroll
        for (int nt = 0; nt < NT; nt++) {
            const bf16x8 wf = *reinterpret_cast<const bf16x8*>(WP + ((size_t)(kt * NT + nt) * 64 + ln) * 8);
            acc[nt] = __builtin_amdgcn_mfma_f32_16x16x32_bf16(af[kt], wf, acc[nt], 0, 0, 0);
        }
    }
}

template<int NT, int DN, bool RELU>
__device__ inline void pack_h(const f32x4 acc[NT], const float* __restrict__ B,
                              unsigned short* __restrict__ Hs, int col, int quad)
{
    #pragma unroll
    for (int nt = 0; nt < NT; nt++) {
        const int n = nt * 16 + col;
        const float b = (n < DN) ? B[n] : 0.f;
        #pragma unroll
        for (int r = 0; r < 4; r++) {
            float v = acc[nt][r] + b;
            if (RELU) v = fmaxf(v, 0.f);
            Hs[(quad * 4 + r) * HS + n] = f2bf(v);
        }
    }
}

template<int NT, int DN>
__device__ inline void store_pack(const f32x4 acc[NT], const float* __restrict__ B,
                                  float* __restrict__ Y, unsigned short* __restrict__ Hs,
                                  int rowbase, int col, int quad, int N)
{
    #pragma unroll
    for (int nt = 0; nt < NT; nt++) {
        const int n = nt * 16 + col;
        const float b = (n < DN) ? B[n] : 0.f;
        #pragma unroll
        for (int r = 0; r < 4; r++) {
            const float v = acc[nt][r] + b;
            const int row = rowbase + quad * 4 + r;
            if (n < DN && row < N) Y[(size_t)row * DN + n] = v;
            Hs[(quad * 4 + r) * HS + n] = f2bf(v);
        }
    }
}

__device__ inline void load_haf(const unsigned short* __restrict__ Hs, int col, int quad,
                                bf16x8 af[4])
{
    const unsigned short* p = Hs + col * HS + quad * 8;
    #pragma unroll
    for (int kt = 0; kt < 4; kt++)
        af[kt] = *reinterpret_cast<const bf16x8*>(p + kt * 32);
}

template<int NT, int DN>
__device__ inline float norm_stage(const f32x4 acc[NT], const float* __restrict__ B,
                                   const float* __restrict__ REF,
                                   int rowbase, int col, int quad, int N)
{
    float ra[4] = {0.f, 0.f, 0.f, 0.f};
    #pragma unroll
    for (int nt = 0; nt < NT; nt++) {
        const int n = nt * 16 + col;
        if (n < DN) {
            const float b = B[n];
            #pragma unroll
            for (int r = 0; r < 4; r++) {
                const int row = rowbase + quad * 4 + r;
                if (row < N) {
                    const float d = acc[nt][r] + b - REF[(size_t)row * DN + n];
                    ra[r] = fmaf(d, d, ra[r]);
                }
            }
        }
    }
    #pragma unroll
    for (int o = 1; o < 16; o <<= 1) {
        #pragma unroll
        for (int r = 0; r < 4; r++) ra[r] += __shfl_xor(ra[r], o);
    }
    float s = 0.f;
    if (col == 0) {
        #pragma unroll
        for (int r = 0; r < 4; r++)
            if (rowbase + quad * 4 + r < N) s += sqrtf(ra[r]);
    }
    return s;
}

// ---------------------------------------------------------------------------
// Fused 4-stage MLP chain body. 2 waves x 16 rows. (R13 form: A from xbf/ybf.)
// ---------------------------------------------------------------------------
template<int DIN, int DMID, int NT2, int NTF>
__device__ __forceinline__ void mlp_chain(
    int bid,
    const unsigned short* __restrict__ Xbf,
    const float* __restrict__ XREF,
    const unsigned short* __restrict__ WP1, const float* __restrict__ B1,
    const unsigned short* __restrict__ WP2, const float* __restrict__ B2,
    const unsigned short* __restrict__ WP3, const float* __restrict__ B3,
    const unsigned short* __restrict__ WP4, const float* __restrict__ B4,
    float* __restrict__ Y, float* __restrict__ part, int N,
    unsigned short (*H)[16 * HS], float* bred)
{
    const int tid = threadIdx.x;
    const int wv = tid >> 6, ln = tid & 63;
    const int col = ln & 15, quad = ln >> 4;
    const int rowbase = bid * 32 + wv * 16;

    {
        unsigned* Hz = reinterpret_cast<unsigned*>(H[wv]);
        for (int i = ln; i < 16 * HS / 2; i += 64) Hz[i] = 0u;
    }

    bf16x8 af[4];
    {
        const int r = min(rowbase + col, N - 1);
        const unsigned short* ap = Xbf + (size_t)r * 128 + quad * 8;
        #pragma unroll
        for (int kt = 0; kt < 4; kt++) af[kt] = *reinterpret_cast<const bf16x8*>(ap + kt * 32);
    }

    f32x4 accA[7];
    run_stage<7>(af, WP1, ln, accA);
    pack_h<7, HIDDEN, true>(accA, B1, H[wv], col, quad);
    load_haf(H[wv], col, quad, af);

    f32x4 accB[NT2];
    run_stage<NT2>(af, WP2, ln, accB);
    store_pack<NT2, DMID>(accB, B2, Y, H[wv], rowbase, col, quad, N);
    load_haf(H[wv], col, quad, af);

    run_stage<7>(af, WP3, ln, accA);
    pack_h<7, HIDDEN, true>(accA, B3, H[wv], col, quad);
    load_haf(H[wv], col, quad, af);

    f32x4 accC[NTF];
    run_stage<NTF>(af, WP4, ln, accC);
    const float s = norm_stage<NTF, DIN>(accC, B4, XREF, rowbase, col, quad, N);

    if (col == 0) bred[wv * 4 + quad] = s;
    __syncthreads();
    if (tid == 0) {
        float t = 0.f;
        #pragma unroll
        for (int i = 0; i < 8; i++) t += bred[i];
        part[bid] = t;
    }
}

__global__ __launch_bounds__(128) void mlp_both(
    const unsigned short* __restrict__ xbf, const float* __restrict__ xw,
    const unsigned short* __restrict__ ybf, const float* __restrict__ yw,
    const unsigned short* __restrict__ wp_fx1, const float* __restrict__ fx_b1,
    const unsigned short* __restrict__ wp_fx2, const float* __restrict__ fx_b2,
    const unsigned short* __restrict__ wp_gy1, const float* __restrict__ gy_b1,
    const unsigned short* __restrict__ wp_gy2, const float* __restrict__ gy_b2,
    float* __restrict__ xm, float* __restrict__ ym,
    float* __restrict__ part, int N)
{
    __shared__ unsigned short H[2][16 * HS];
    __shared__ float bred[8];
    if (blockIdx.x < GM) {
        mlp_chain<100, 120, 8, 7>(blockIdx.x, xbf, xw,
            wp_fx1, fx_b1, wp_fx2, fx_b2, wp_gy1, gy_b1, wp_gy2, gy_b2,
            xm, part, N, H, bred);
    } else {
        mlp_chain<120, 100, 7, 8>(blockIdx.x - GM, ybf, yw,
            wp_gy1, gy_b1, wp_gy2, gy_b2, wp_fx1, fx_b1, wp_fx2, fx_b2,
            ym, part + GM, N, H, bred);
    }
}

// ---------------------------------------------------------------------------
// sup + gather fused: wave per pair; also emits -2-scaled bf16 query panels.
// ---------------------------------------------------------------------------
__global__ __launch_bounds__(256) void sup_gather(
    const float* __restrict__ xm, const float* __restrict__ ym,
    const float* __restrict__ xw, const float* __restrict__ yw,
    const int* __restrict__ im, int K, float* __restrict__ part,
    unsigned short* __restrict__ axf, unsigned short* __restrict__ ayf)
{
    const int gw = (int)((blockIdx.x * 256 + threadIdx.x) >> 6);
    const int ln = threadIdx.x & 63;
    const int wv = threadIdx.x >> 6;
    float cnt = 0.f;
    if (gw < K) {
        const int xi = im[2 * gw], yi = im[2 * gw + 1];
        const float* a = xm + (size_t)xi * 120;
        const float* b = yw + (size_t)yi * 120;
        const float a0 = a[ln];
        const float a1 = (ln + 64 < 120) ? a[ln + 64] : 0.f;
        float s1 = 0.f;
        { const float d0 = a0 - b[ln]; s1 = d0 * d0; }
        if (ln + 64 < 120) { const float d1 = a1 - b[ln + 64]; s1 = fmaf(d1, d1, s1); }
        unsigned short* pax = axf + (size_t)gw * 128;
        pax[ln] = f2bf(-2.f * a0);
        pax[ln + 64] = (ln == 63) ? f2bf(1.f) : ((ln + 64 < 120) ? f2bf(-2.f * a1) : (unsigned short)0);

        const float* c = ym + (size_t)yi * 100;
        const float* e = xw + (size_t)xi * 100;
        const float c0 = c[ln];
        const float c1 = (ln + 64 < 100) ? c[ln + 64] : 0.f;
        float s2 = 0.f;
        { const float d0 = c0 - e[ln]; s2 = d0 * d0; }
        if (ln + 64 < 100) { const float d1 = c1 - e[ln + 64]; s2 = fmaf(d1, d1, s2); }
        unsigned short* pay = ayf + (size_t)gw * 128;
        pay[ln] = f2bf(-2.f * c0);
        pay[ln + 64] = (ln == 63) ? f2bf(1.f) : ((ln + 64 < 100) ? f2bf(-2.f * c1) : (unsigned short)0);

        #pragma unroll
        for (int o = 32; o > 0; o >>= 1) { s1 += __shfl_down(s1, o); s2 += __shfl_down(s2, o); }
        if (ln == 0) cnt = sqrtf(s1) + sqrtf(s2);
    }
    __shared__ float wsum[4];
    if (ln == 0) wsum[wv] = cnt;
    __syncthreads();
    if (threadIdx.x == 0)
        part[blockIdx.x] = wsum[0] + wsum[1] + wsum[2] + wsum[3];
}

// ---------------------------------------------------------------------------
// 16B global->LDS DMA for one 32x128 bf16 tile (8 KB), XOR-swizzled.
// ---------------------------------------------------------------------------
__device__ inline void stage32(const unsigned short* __restrict__ T, int jbase,
                               unsigned char* dst0, int wv, int ln)
{
    #pragma unroll
    for (int h = 0; h < 2; h++) {
        const int c = h * 256 + wv * 64 + ln;
        const int r = c >> 4;
        const int gc = (c & 15) ^ (r & 15);
        const unsigned short* g = T + ((size_t)(jbase + r) << 7) + gc * 8;
        unsigned char* l = dst0 + h * 4096 + wv * 1024;
        __builtin_amdgcn_global_load_lds(
            (const __attribute__((address_space(1))) void*)g,
            (__attribute__((address_space(3))) void*)l, 16, 0, 0);
    }
}

// ---------------------------------------------------------------------------
// MFMA 1-NN v8: R13 structure (16x16x32, 256-row blocks, 64-row double-step,
// DMA staging, XOR swizzle) + issue-slimmed min-update: mask/low forced into
// VGPRs (v_and_or_b32 single-op) and subtile pair folded with v_min3_f32 --
// update VALU per element drops ~3 -> ~1.5 issues. (256,3): the only
// empirically no-spill bound (R6/R7/R12 spill history). Spill tripwire:
// WRITE_SIZE >> 6 MB.
// ---------------------------------------------------------------------------
__global__ __launch_bounds__(256, 3) void nn_mfma(
    const unsigned short* __restrict__ A0, const unsigned short* __restrict__ T0,
    float* __restrict__ pm0, int* __restrict__ pi0,
    const unsigned short* __restrict__ A1, const unsigned short* __restrict__ T1,
    float* __restrict__ pm1, int* __restrict__ pi1,
    int K)
{
    __shared__ __align__(16) unsigned char smem[32768];
    float (*rm)[64][17] = reinterpret_cast<float(*)[64][17]>(smem);

    const unsigned short* A = blockIdx.z ? A1 : A0;
    const unsigned short* T = blockIdx.z ? T1 : T0;
    float* pmin = blockIdx.z ? pm1 : pm0;
    int*   pidx = blockIdx.z ? pi1 : pi0;

    const int tid = threadIdx.x;
    const int wv = tid >> 6, ln = tid & 63;
    const int col = ln & 15, quad = ln >> 4;
    const int k0 = blockIdx.x * 256;
    const int jstart = blockIdx.y * CHUNK;
    constexpr int NSTEPS = CHUNK / 64;   // 14

    bf16x8 afrag[4][4];
    #pragma unroll
    for (int t = 0; t < 4; t++) {
        const int ar = min(k0 + wv * 64 + t * 16 + col, K - 1);
        const unsigned short* ab = A + (size_t)ar * 128 + quad * 8;
        #pragma unroll
        for (int s = 0; s < 4; s++)
            afrag[t][s] = *reinterpret_cast<const bf16x8*>(ab + s * 32);
    }

    float m[4][4];
    #pragma unroll
    for (int t = 0; t < 4; t++)
        #pragma unroll
        for (int r = 0; r < 4; r++) m[t][r] = __builtin_inff();

    const unsigned vmask = vmov(0xFFFFF800u);   // VGPR-resident mask

    stage32(T, jstart,      smem,        wv, ln);
    stage32(T, jstart + 32, smem + 8192, wv, ln);
    __syncthreads();

    for (int ti = 0; ti < NSTEPS; ti++) {
        const int cur = ti & 1;
        if (ti + 1 < NSTEPS) {
            const int jn = jstart + (ti + 1) * 64;
            stage32(T, jn,      smem + (cur ^ 1) * 16384,        wv, ln);
            stage32(T, jn + 32, smem + (cur ^ 1) * 16384 + 8192, wv, ln);
        }

        #pragma unroll
        for (int h = 0; h < 2; h++) {
            const unsigned short* base = (const unsigned short*)(smem + cur * 16384 + h * 8192);
            const unsigned lowbase = (unsigned)((jstart + ti * 64 + h * 32) >> 4);
            const unsigned vl0 = vmov(lowbase);
            const unsigned vl1 = vmov(lowbase + 1);

            f32x4 acc0[4], acc1[4];
            {   // subtile 0 (rows col)
                bf16x8 bfr[4];
                #pragma unroll
                for (int s = 0; s < 4; s++) {
                    const int ch = col * 16 + ((quad + s * 4) ^ col);
                    bfr[s] = *reinterpret_cast<const bf16x8*>(base + ch * 8);
                }
                #pragma unroll
                for (int t = 0; t < 4; t++) {
                    f32x4 acc = {0.f, 0.f, 0.f, 0.f};
                    #pragma unroll
                    for (int s = 0; s < 4; s++)
                        acc = __builtin_amdgcn_mfma_f32_16x16x32_bf16(afrag[t][s], bfr[s], acc, 0, 0, 0);
                    acc0[t] = acc;
                }
            }
            {   // subtile 1 (rows 16+col)
                bf16x8 bfr[4];
                #pragma unroll
                for (int s = 0; s < 4; s++) {
                    const int ch = (16 + col) * 16 + ((quad + s * 4) ^ col);
                    bfr[s] = *reinterpret_cast<const bf16x8*>(base + ch * 8);
                }
                #pragma unroll
                for (int t = 0; t < 4; t++) {
                    f32x4 acc = {0.f, 0.f, 0.f, 0.f};
                    #pragma unroll
                    for (int s = 0; s < 4; s++)
                        acc = __builtin_amdgcn_mfma_f32_16x16x32_bf16(afrag[t][s], bfr[s], acc, 0, 0, 0);
                    acc1[t] = acc;
                }
            }
            #pragma unroll
            for (int t = 0; t < 4; t++) {
                #pragma unroll
                for (int r = 0; r < 4; r++) {
                    const unsigned u0 = (__float_as_uint(acc0[t][r]) & vmask) | vl0;
                    const unsigned u1 = (__float_as_uint(acc1[t][r]) & vmask) | vl1;
                    m[t][r] = fminf(m[t][r],
                                    fminf(__uint_as_float(u0), __uint_as_float(u1)));
                }
            }
        }
        __syncthreads();
    }

    #pragma unroll
    for (int t = 0; t < 4; t++)
        #pragma unroll
        for (int r = 0; r < 4; r++)
            rm[wv][t * 16 + quad * 4 + r][col] = m[t][r];
    __syncthreads();

    const int k = k0 + tid;
    if (k < K) {
        const int w = tid >> 6, rr = tid & 63;
        float best = rm[w][rr][0];
        int bc = 0;
        #pragma unroll
        for (int c = 1; c < 16; c++) {
            const float v = rm[w][rr][c];
            if (v < best) { best = v; bc = c; }
        }
        const int j = (int)(((__float_as_uint(best) & 0x7FFu) << 4) | (unsigned)bc);
        pmin[(size_t)k * NC + blockIdx.y] = best;
        pidx[(size_t)k * NC + blockIdx.y] = j;
    }
}

// ---------------------------------------------------------------------------
// finish_all: mismatch indicators + sup partials + mlp partials. 64 atomics.
// ---------------------------------------------------------------------------
__global__ __launch_bounds__(256) void finish_all(
    const int* __restrict__ im,
    const float* __restrict__ pm0, const int* __restrict__ pi0,
    const float* __restrict__ pm1, const int* __restrict__ pi1,
    const float* __restrict__ part_sup, const float* __restrict__ part_mlp,
    int K, float* __restrict__ out, float inv_k, float inv_n)
{
    const int gid = blockIdx.x * 256 + threadIdx.x;
    const int stride = gridDim.x * 256;
    float local = 0.f;

    for (int p = gid; p < 2 * K; p += stride) {
        const int dir = (p >= K);
        const int kk = dir ? p - K : p;
        const float* pm = dir ? pm1 : pm0;
        const int*   pi = dir ? pi1 : pi0;
        float best = __builtin_inff();
        int bi = 0x7fffffff;
        #pragma unroll
        for (int c = 0; c < NC; c++) {
            const float v = pm[(size_t)kk * NC + c];
            const int  ii = pi[(size_t)kk * NC + c];
            if (v < best || (v == best && ii < bi)) { best = v; bi = ii; }
        }
        if (bi != im[2 * kk + dir]) local += inv_k;
    }
    for (int i = gid; i < NB_SUP; i += stride) local += part_sup[i] * inv_k;
    for (int i = gid; i < NB_MLP; i += stride) local += part_mlp[i] * inv_n;

    #pragma unroll
    for (int o = 32; o > 0; o >>= 1) local += __shfl_down(local, o);
    __shared__ float wsum[4];
    if ((threadIdx.x & 63) == 0) wsum[threadIdx.x >> 6] = local;
    __syncthreads();
    if (threadIdx.x == 0) {
        const float t = wsum[0] + wsum[1] + wsum[2] + wsum[3];
        if (t != 0.f) atomicAdd(out, t);
    }
}

// ---------------------------------------------------------------------------
extern "C" void kernel_launch(void* const* d_in, const int* in_sizes, int n_in,
                              void* d_out, int out_size, void* d_ws, size_t ws_size,
                              hipStream_t stream)
{
    const float* xw    = (const float*)d_in[0];
    const float* yw    = (const float*)d_in[1];
    const float* fx_w1 = (const float*)d_in[2];
    const float* fx_b1 = (const float*)d_in[3];
    const float* fx_w2 = (const float*)d_in[4];
    const float* fx_b2 = (const float*)d_in[5];
    const float* gy_w1 = (const float*)d_in[6];
    const float* gy_b1 = (const float*)d_in[7];
    const float* gy_w2 = (const float*)d_in[8];
    const float* gy_b2 = (const float*)d_in[9];
    const int*   imap  = (const int*)d_in[10];
    float* out = (float*)d_out;
    float* ws  = (float*)d_ws;

    constexpr int N = NPTS, K = KPAIR;

    float* xm      = ws;                           // N*120
    float* ym      = xm + (size_t)N * 120;         // N*100
    float* pmin_fx = ym + (size_t)N * 100;         // K*NC
    int*   pidx_fx = (int*)(pmin_fx + (size_t)K * NC);
    float* pmin_gy = (float*)(pidx_fx + (size_t)K * NC);
    int*   pidx_gy = (int*)(pmin_gy + (size_t)K * NC);
    unsigned short* ybf = (unsigned short*)(pidx_gy + (size_t)K * NC); // NPAD*128
    unsigned short* xbf = ybf + (size_t)NPAD * 128;                    // NPAD*128
    unsigned short* axf = xbf + (size_t)NPAD * 128;  // K*128
    unsigned short* ayf = axf + (size_t)K * 128;
    unsigned short* wp_fx1 = ayf + (size_t)K * 128;  // 28*512
    unsigned short* wp_fx2 = wp_fx1 + 28 * 512;      // 32*512
    unsigned short* wp_gy1 = wp_fx2 + 32 * 512;      // 28*512
    unsigned short* wp_gy2 = wp_gy1 + 28 * 512;      // 28*512
    float* part_sup = (float*)(wp_gy2 + 28 * 512);   // NB_SUP
    float* part_mlp = part_sup + NB_SUP;             // NB_MLP

    hipMemsetAsync(d_out, 0, sizeof(float), stream);

    prep_kernel<<<PREP_B + 29, 256, 0, stream>>>(
        yw, ybf, xw, xbf,
        fx_w1, wp_fx1, fx_w2, wp_fx2, gy_w1, wp_gy1, gy_w2, wp_gy2, N);

    mlp_both<<<2 * GM, 128, 0, stream>>>(
        xbf, xw, ybf, yw,
        wp_fx1, fx_b1, wp_fx2, fx_b2, wp_gy1, gy_b1, wp_gy2, gy_b2,
        xm, ym, part_mlp, N);

    sup_gather<<<NB_SUP, 256, 0, stream>>>(xm, ym, xw, yw, imap, K, part_sup, axf, ayf);

    dim3 g1((K + 255) / 256, NC, 2);
    nn_mfma<<<g1, 256, 0, stream>>>(axf, ybf, pmin_fx, pidx_fx,
                                    ayf, xbf, pmin_gy, pidx_gy, K);

    finish_all<<<64, 256, 0, stream>>>(
        imap, pmin_fx, pidx_fx, pmin_gy, pidx_gy, part_sup, part_mlp,
        K, out, 1.f / K, 1.f / N);
}

// Round 16
// 198.952 us; speedup vs baseline: 1.1375x; 1.0963x over previous
//
#include <hip/hip_runtime.h>
#include <hip/hip_bf16.h>
#include <math.h>

#define HIDDEN 100

typedef __attribute__((ext_vector_type(8))) short bf16x8;
typedef __attribute__((ext_vector_type(8))) int   i32x8;
typedef __attribute__((ext_vector_type(4))) float f32x4;

__device__ inline unsigned short f2bf(float v) {
    union { float f; unsigned u; } x; x.f = v;
    unsigned r = x.u + 0x7fff + ((x.u >> 16) & 1);   // RNE
    return (unsigned short)(r >> 16);
}

__device__ inline unsigned char f2fp8(float v) {    // OCP e4m3
    return (unsigned char)(__builtin_amdgcn_cvt_pk_fp8_f32(v, 0.f, 0, false) & 0xFF);
}

constexpr int NPTS  = 25000;
constexpr int KPAIR = 8000;
constexpr int NC    = 28;
constexpr int CHUNK = 896;          // multiple of 64; 28*896 = 25088
constexpr int NPAD  = NC * CHUNK;   // padded target rows (25088)
constexpr int HS    = 136;          // LDS H-slab stride (shorts) for mlp
constexpr int NB_SUP = 2000;
constexpr int GM     = (NPTS + 31) / 32;   // 782 mlp blocks per dir
constexpr int NB_MLP = 2 * GM;
constexpr int PREP_B = (2 * NPAD) / 16;    // 3136 row-prep blocks

// ---------------------------------------------------------------------------
// prep: fp8 target panels (128 B/row) + fp32 tn (pad rows: zeros + tn=1e30).
// Tail blocks: bf16 weight panels for the MLP (unchanged).
// ---------------------------------------------------------------------------
__global__ __launch_bounds__(256) void prep_kernel(
    const float* __restrict__ YW, unsigned char* __restrict__ ybf8, float* __restrict__ tny,
    const float* __restrict__ XW, unsigned char* __restrict__ xbf8, float* __restrict__ tnx,
    const float* __restrict__ W1, unsigned short* __restrict__ P1,
    const float* __restrict__ W2, unsigned short* __restrict__ P2,
    const float* __restrict__ W3, unsigned short* __restrict__ P3,
    const float* __restrict__ W4, unsigned short* __restrict__ P4,
    int N)
{
    const int ln = threadIdx.x & 63;
    if (blockIdx.x < PREP_B) {
        const int g0 = blockIdx.x * 16 + (threadIdx.x >> 6) * 4;
        #pragma unroll
        for (int i = 0; i < 4; i++) {
            const int gw = g0 + i;
            const int isY = (gw < NPAD);
            const int r = isY ? gw : gw - NPAD;
            const int D = isY ? 120 : 100;
            unsigned char* dst = (isY ? ybf8 : xbf8) + (size_t)r * 128;
            if (r < N) {
                const float* src = (isY ? YW : XW) + (size_t)r * D;
                const float v0 = (ln < D) ? src[ln] : 0.f;
                const float v1 = (ln + 64 < D) ? src[ln + 64] : 0.f;
                float s = fmaf(v0, v0, v1 * v1);
                #pragma unroll
                for (int o = 1; o < 64; o <<= 1) s += __shfl_xor(s, o);
                if (ln == 0) (isY ? tny : tnx)[r] = s;
                dst[ln] = f2fp8(v0);
                dst[ln + 64] = f2fp8(v1);
            } else {
                dst[ln] = 0;
                dst[ln + 64] = 0;
                if (ln == 0) (isY ? tny : tnx)[r] = 1e30f;
            }
        }
        return;
    }
    // ---- weight panel prep (bf16, MLP) ----
    int b = (blockIdx.x - PREP_B) * 4 + (threadIdx.x >> 6);
    if (b >= 116) return;
    const float* W; unsigned short* P; int DK, DN, NT;
    if (b < 28)      {          W = W1; P = P1; DK = 100; DN = 100; NT = 7; }
    else if (b < 60) { b -= 28; W = W2; P = P2; DK = 100; DN = 120; NT = 8; }
    else if (b < 88) { b -= 60; W = W3; P = P3; DK = 120; DN = 100; NT = 7; }
    else             { b -= 88; W = W4; P = P4; DK = 100; DN = 100; NT = 7; }
    const int kt = b / NT, nt = b - kt * NT;
    const int n  = nt * 16 + (ln & 15);
    const int k0 = kt * 32 + (ln >> 4) * 8;
    unsigned short* dst = P + ((size_t)(kt * NT + nt) * 64 + ln) * 8;
    #pragma unroll
    for (int j = 0; j < 8; j++) {
        const int k = k0 + j;
        const float f = (k < DK && n < DN) ? W[k * DN + n] : 0.f;
        dst[j] = f2bf(f);
    }
}

// ---------------------------------------------------------------------------
// MFMA stage helpers for the MLP (16x16x32 bf16, verified R2-R15).
// ---------------------------------------------------------------------------
template<int NT>
__device__ inline void run_stage(const bf16x8 af[4], const unsigned short* __restrict__ WP,
                                 int ln, f32x4 acc[NT])
{
    #pragma unroll
    for (int nt = 0; nt < NT; nt++) acc[nt] = (f32x4){0.f, 0.f, 0.f, 0.f};
    #pragma unroll
    for (int kt = 0; kt < 4; kt++) {
        #pragma unroll
        for (int nt = 0; nt < NT; nt++) {
            const bf16x8 wf = *reinterpret_cast<const bf16x8*>(WP + ((size_t)(kt * NT + nt) * 64 + ln) * 8);
            acc[nt] = __builtin_amdgcn_mfma_f32_16x16x32_bf16(af[kt], wf, acc[nt], 0, 0, 0);
        }
    }
}

template<int NT, int DN, bool RELU>
__device__ inline void pack_h(const f32x4 acc[NT], const float* __restrict__ B,
                              unsigned short* __restrict__ Hs, int col, int quad)
{
    #pragma unroll
    for (int nt = 0; nt < NT; nt++) {
        const int n = nt * 16 + col;
        const float b = (n < DN) ? B[n] : 0.f;
        #pragma unroll
        for (int r = 0; r < 4; r++) {
            float v = acc[nt][r] + b;
            if (RELU) v = fmaxf(v, 0.f);
            Hs[(quad * 4 + r) * HS + n] = f2bf(v);
        }
    }
}

template<int NT, int DN>
__device__ inline void store_pack(const f32x4 acc[NT], const float* __restrict__ B,
                                  float* __restrict__ Y, unsigned short* __restrict__ Hs,
                                  int rowbase, int col, int quad, int N)
{
    #pragma unroll
    for (int nt = 0; nt < NT; nt++) {
        const int n = nt * 16 + col;
        const float b = (n < DN) ? B[n] : 0.f;
        #pragma unroll
        for (int r = 0; r < 4; r++) {
            const float v = acc[nt][r] + b;
            const int row = rowbase + quad * 4 + r;
            if (n < DN && row < N) Y[(size_t)row * DN + n] = v;
            Hs[(quad * 4 + r) * HS + n] = f2bf(v);
        }
    }
}

__device__ inline void load_haf(const unsigned short* __restrict__ Hs, int col, int quad,
                                bf16x8 af[4])
{
    const unsigned short* p = Hs + col * HS + quad * 8;
    #pragma unroll
    for (int kt = 0; kt < 4; kt++)
        af[kt] = *reinterpret_cast<const bf16x8*>(p + kt * 32);
}

// Direct fp32 -> A-frag (verified R14, absmax 0.0): garbage beyond DIN hits
// zero-padded weight rows.
template<int DIN>
__device__ inline void load_a_direct(const float* __restrict__ X, int r, int quad,
                                     bf16x8 af[4])
{
    const float* ap = X + (size_t)r * DIN;
    #pragma unroll
    for (int kt = 0; kt < 4; kt++) {
        const int base = kt * 32 + quad * 8;
        float4 v0, v1;
        if (DIN == 100) {
            if (base == 96) {
                v0 = *reinterpret_cast<const float4*>(ap + 96);
                v1 = make_float4(0.f, 0.f, 0.f, 0.f);
            } else {
                const int b = (base < 92) ? base : 92;
                v0 = *reinterpret_cast<const float4*>(ap + b);
                v1 = *reinterpret_cast<const float4*>(ap + b + 4);
            }
        } else {
            const int b = (base < 112) ? base : 112;
            v0 = *reinterpret_cast<const float4*>(ap + b);
            v1 = *reinterpret_cast<const float4*>(ap + b + 4);
        }
        bf16x8 f;
        f[0] = (short)f2bf(v0.x); f[1] = (short)f2bf(v0.y);
        f[2] = (short)f2bf(v0.z); f[3] = (short)f2bf(v0.w);
        f[4] = (short)f2bf(v1.x); f[5] = (short)f2bf(v1.y);
        f[6] = (short)f2bf(v1.z); f[7] = (short)f2bf(v1.w);
        af[kt] = f;
    }
}

template<int NT, int DN>
__device__ inline float norm_stage(const f32x4 acc[NT], const float* __restrict__ B,
                                   const float* __restrict__ REF,
                                   int rowbase, int col, int quad, int N)
{
    float ra[4] = {0.f, 0.f, 0.f, 0.f};
    #pragma unroll
    for (int nt = 0; nt < NT; nt++) {
        const int n = nt * 16 + col;
        if (n < DN) {
            const float b = B[n];
            #pragma unroll
            for (int r = 0; r < 4; r++) {
                const int row = rowbase + quad * 4 + r;
                if (row < N) {
                    const float d = acc[nt][r] + b - REF[(size_t)row * DN + n];
                    ra[r] = fmaf(d, d, ra[r]);
                }
            }
        }
    }
    #pragma unroll
    for (int o = 1; o < 16; o <<= 1) {
        #pragma unroll
        for (int r = 0; r < 4; r++) ra[r] += __shfl_xor(ra[r], o);
    }
    float s = 0.f;
    if (col == 0) {
        #pragma unroll
        for (int r = 0; r < 4; r++)
            if (rowbase + quad * 4 + r < N) s += sqrtf(ra[r]);
    }
    return s;
}

// ---------------------------------------------------------------------------
// Fused 4-stage MLP chain (R13 structure, R14 direct-fp32 A loads).
// ---------------------------------------------------------------------------
template<int DIN, int DMID, int NT2, int NTF>
__device__ __forceinline__ void mlp_chain(
    int bid,
    const float* __restrict__ XREF,
    const unsigned short* __restrict__ WP1, const float* __restrict__ B1,
    const unsigned short* __restrict__ WP2, const float* __restrict__ B2,
    const unsigned short* __restrict__ WP3, const float* __restrict__ B3,
    const unsigned short* __restrict__ WP4, const float* __restrict__ B4,
    float* __restrict__ Y, float* __restrict__ part, int N,
    unsigned short (*H)[16 * HS], float* bred)
{
    const int tid = threadIdx.x;
    const int wv = tid >> 6, ln = tid & 63;
    const int col = ln & 15, quad = ln >> 4;
    const int rowbase = bid * 32 + wv * 16;

    {
        unsigned* Hz = reinterpret_cast<unsigned*>(H[wv]);
        for (int i = ln; i < 16 * HS / 2; i += 64) Hz[i] = 0u;
    }

    bf16x8 af[4];
    load_a_direct<DIN>(XREF, min(rowbase + col, N - 1), quad, af);

    f32x4 accA[7];
    run_stage<7>(af, WP1, ln, accA);
    pack_h<7, HIDDEN, true>(accA, B1, H[wv], col, quad);
    load_haf(H[wv], col, quad, af);

    f32x4 accB[NT2];
    run_stage<NT2>(af, WP2, ln, accB);
    store_pack<NT2, DMID>(accB, B2, Y, H[wv], rowbase, col, quad, N);
    load_haf(H[wv], col, quad, af);

    run_stage<7>(af, WP3, ln, accA);
    pack_h<7, HIDDEN, true>(accA, B3, H[wv], col, quad);
    load_haf(H[wv], col, quad, af);

    f32x4 accC[NTF];
    run_stage<NTF>(af, WP4, ln, accC);
    const float s = norm_stage<NTF, DIN>(accC, B4, XREF, rowbase, col, quad, N);

    if (col == 0) bred[wv * 4 + quad] = s;
    __syncthreads();
    if (tid == 0) {
        float t = 0.f;
        #pragma unroll
        for (int i = 0; i < 8; i++) t += bred[i];
        part[bid] = t;
    }
}

__global__ __launch_bounds__(128) void mlp_both(
    const float* __restrict__ xw, const float* __restrict__ yw,
    const unsigned short* __restrict__ wp_fx1, const float* __restrict__ fx_b1,
    const unsigned short* __restrict__ wp_fx2, const float* __restrict__ fx_b2,
    const unsigned short* __restrict__ wp_gy1, const float* __restrict__ gy_b1,
    const unsigned short* __restrict__ wp_gy2, const float* __restrict__ gy_b2,
    float* __restrict__ xm, float* __restrict__ ym,
    float* __restrict__ part, int N)
{
    __shared__ unsigned short H[2][16 * HS];
    __shared__ float bred[8];
    if (blockIdx.x < GM) {
        mlp_chain<100, 120, 8, 7>(blockIdx.x, xw,
            wp_fx1, fx_b1, wp_fx2, fx_b2, wp_gy1, gy_b1, wp_gy2, gy_b2,
            xm, part, N, H, bred);
    } else {
        mlp_chain<120, 100, 7, 8>(blockIdx.x - GM, yw,
            wp_gy1, gy_b1, wp_gy2, gy_b2, wp_fx1, fx_b1, wp_fx2, fx_b2,
            ym, part + GM, N, H, bred);
    }
}

// ---------------------------------------------------------------------------
// sup + gather fused: wave per pair; emits -2-scaled fp8 query panels.
// ---------------------------------------------------------------------------
__global__ __launch_bounds__(256) void sup_gather(
    const float* __restrict__ xm, const float* __restrict__ ym,
    const float* __restrict__ xw, const float* __restrict__ yw,
    const int* __restrict__ im, int K, float* __restrict__ part,
    unsigned char* __restrict__ axf8, unsigned char* __restrict__ ayf8)
{
    const int gw = (int)((blockIdx.x * 256 + threadIdx.x) >> 6);
    const int ln = threadIdx.x & 63;
    const int wv = threadIdx.x >> 6;
    float cnt = 0.f;
    if (gw < K) {
        const int xi = im[2 * gw], yi = im[2 * gw + 1];
        const float* a = xm + (size_t)xi * 120;
        const float* b = yw + (size_t)yi * 120;
        const float a0 = a[ln];
        const float a1 = (ln + 64 < 120) ? a[ln + 64] : 0.f;
        float s1 = 0.f;
        { const float d0 = a0 - b[ln]; s1 = d0 * d0; }
        if (ln + 64 < 120) { const float d1 = a1 - b[ln + 64]; s1 = fmaf(d1, d1, s1); }
        unsigned char* pax = axf8 + (size_t)gw * 128;
        pax[ln] = f2fp8(-2.f * a0);
        pax[ln + 64] = f2fp8(-2.f * a1);

        const float* c = ym + (size_t)yi * 100;
        const float* e = xw + (size_t)xi * 100;
        const float c0 = c[ln];
        const float c1 = (ln + 64 < 100) ? c[ln + 64] : 0.f;
        float s2 = 0.f;
        { const float d0 = c0 - e[ln]; s2 = d0 * d0; }
        if (ln + 64 < 100) { const float d1 = c1 - e[ln + 64]; s2 = fmaf(d1, d1, s2); }
        unsigned char* pay = ayf8 + (size_t)gw * 128;
        pay[ln] = f2fp8(-2.f * c0);
        pay[ln + 64] = f2fp8(-2.f * c1);

        #pragma unroll
        for (int o = 32; o > 0; o >>= 1) { s1 += __shfl_down(s1, o); s2 += __shfl_down(s2, o); }
        if (ln == 0) cnt = sqrtf(s1) + sqrtf(s2);
    }
    __shared__ float wsum[4];
    if (ln == 0) wsum[wv] = cnt;
    __syncthreads();
    if (threadIdx.x == 0)
        part[blockIdx.x] = wsum[0] + wsum[1] + wsum[2] + wsum[3];
}

// ---------------------------------------------------------------------------
// 16B DMA for one 32x128 fp8 tile (4 KB), XOR-swizzled: tile chunk c
// (r=c>>3, slot=c&7) holds global chunk slot^(r&7) of row r.
// ---------------------------------------------------------------------------
__device__ inline void stage32f8(const unsigned char* __restrict__ T, int jbase,
                                 unsigned char* dst0, int wv, int ln)
{
    const int c = wv * 64 + ln;         // 0..255
    const int r = c >> 3;
    const int gc = (c & 7) ^ (r & 7);
    const unsigned char* g = T + ((size_t)(jbase + r) << 7) + gc * 16;
    unsigned char* l = dst0 + wv * 1024 + ln * 16;
    __builtin_amdgcn_global_load_lds(
        (const __attribute__((address_space(1))) void*)g,
        (__attribute__((address_space(3))) void*)l, 16, 0, 0);
}

// ---------------------------------------------------------------------------
// MFMA 1-NN v9: MX-fp8 16x16x128 (K=128 in ONE MFMA; ~2x bf16 rate, m21/m148).
// A = -2*query (fp8 e4m3), B = targets (fp8); tn added in fp32 post-MFMA
// (avoids fp8-quantizing tn). Scales = 1.0 (e8m0 0x7F). Same 256-row block /
// 64-row double-step / DMA / XOR-swizzle / mantissa-packed j>>4 as R13.
// A-frag: m=lane&15, k=(lane>>4)*32+byte. C: col=lane&15, row=quad*4+reg
// (C/D layout is shape-determined, dtype-independent: m121-m128).
// ---------------------------------------------------------------------------
__global__ __launch_bounds__(256, 3) void nn_mfma(
    const unsigned char* __restrict__ A0, const unsigned char* __restrict__ T0,
    const float* __restrict__ TN0, float* __restrict__ pm0, int* __restrict__ pi0,
    const unsigned char* __restrict__ A1, const unsigned char* __restrict__ T1,
    const float* __restrict__ TN1, float* __restrict__ pm1, int* __restrict__ pi1,
    int K)
{
    __shared__ __align__(16) unsigned char smem[17408];   // 2 x (2x4 KB) step bufs; rm alias
    float (*rm)[64][17] = reinterpret_cast<float(*)[64][17]>(smem);

    const unsigned char* A = blockIdx.z ? A1 : A0;
    const unsigned char* T = blockIdx.z ? T1 : T0;
    const float* TN = blockIdx.z ? TN1 : TN0;
    float* pmin = blockIdx.z ? pm1 : pm0;
    int*   pidx = blockIdx.z ? pi1 : pi0;

    const int tid = threadIdx.x;
    const int wv = tid >> 6, ln = tid & 63;
    const int col = ln & 15, quad = ln >> 4;
    const int k0 = blockIdx.x * 256;
    const int jstart = blockIdx.y * CHUNK;
    constexpr int NSTEPS = CHUNK / 64;   // 14

    // A fragments: 4 rowtiles x 8 dwords (32 fp8 bytes = full K=128).
    i32x8 afrag[4];
    #pragma unroll
    for (int t = 0; t < 4; t++) {
        const int ar = min(k0 + wv * 64 + t * 16 + col, K - 1);
        const uint4* ab = reinterpret_cast<const uint4*>(A + (size_t)ar * 128 + quad * 32);
        const uint4 lo = ab[0], hi = ab[1];
        afrag[t] = (i32x8){(int)lo.x, (int)lo.y, (int)lo.z, (int)lo.w,
                           (int)hi.x, (int)hi.y, (int)hi.z, (int)hi.w};
    }

    float m[4][4];
    #pragma unroll
    for (int t = 0; t < 4; t++)
        #pragma unroll
        for (int r = 0; r < 4; r++) m[t][r] = __builtin_inff();

    stage32f8(T, jstart,      smem,        wv, ln);
    stage32f8(T, jstart + 32, smem + 4096, wv, ln);
    __syncthreads();

    for (int ti = 0; ti < NSTEPS; ti++) {
        const int cur = ti & 1;
        const int jbase = jstart + ti * 64;
        if (ti + 1 < NSTEPS) {
            stage32f8(T, jbase + 64, smem + (cur ^ 1) * 8192,        wv, ln);
            stage32f8(T, jbase + 96, smem + (cur ^ 1) * 8192 + 4096, wv, ln);
        }

        float tnv[2][2];
        #pragma unroll
        for (int h = 0; h < 2; h++)
            #pragma unroll
            for (int sub = 0; sub < 2; sub++)
                tnv[h][sub] = TN[jbase + h * 32 + sub * 16 + col];

        #pragma unroll
        for (int h = 0; h < 2; h++) {
            const unsigned char* base = smem + cur * 8192 + h * 4096;
            const unsigned lowbase = (unsigned)((jbase + h * 32) >> 4);
            #pragma unroll
            for (int sub = 0; sub < 2; sub++) {
                const int rT = sub * 16 + col;
                const uint4 lo = *reinterpret_cast<const uint4*>(
                    base + (rT * 8 + ((2 * quad + 0) ^ (rT & 7))) * 16);
                const uint4 hi = *reinterpret_cast<const uint4*>(
                    base + (rT * 8 + ((2 * quad + 1) ^ (rT & 7))) * 16);
                const i32x8 bfr = (i32x8){(int)lo.x, (int)lo.y, (int)lo.z, (int)lo.w,
                                          (int)hi.x, (int)hi.y, (int)hi.z, (int)hi.w};
                const unsigned low = lowbase + sub;
                const float tval = tnv[h][sub];
                #pragma unroll
                for (int t = 0; t < 4; t++) {
                    f32x4 acc = {0.f, 0.f, 0.f, 0.f};
                    acc = __builtin_amdgcn_mfma_scale_f32_16x16x128_f8f6f4(
                        afrag[t], bfr, acc, 0, 0, 0, 0x7F7F7F7F, 0, 0x7F7F7F7F);
                    #pragma unroll
                    for (int r = 0; r < 4; r++) {
                        const float val = acc[r] + tval;
                        const unsigned u = (__float_as_uint(val) & 0xFFFFF800u) | low;
                        m[t][r] = fminf(m[t][r], __uint_as_float(u));
                    }
                }
            }
        }
        __syncthreads();
    }

    // ---- reduction (rm aliases smem; all tile reads complete) ----
    #pragma unroll
    for (int t = 0; t < 4; t++)
        #pragma unroll
        for (int r = 0; r < 4; r++)
            rm[wv][t * 16 + quad * 4 + r][col] = m[t][r];
    __syncthreads();

    const int k = k0 + tid;
    if (k < K) {
        const int w = tid >> 6, rr = tid & 63;
        float best = rm[w][rr][0];
        int bc = 0;
        #pragma unroll
        for (int c = 1; c < 16; c++) {
            const float v = rm[w][rr][c];
            if (v < best) { best = v; bc = c; }
        }
        const int j = (int)(((__float_as_uint(best) & 0x7FFu) << 4) | (unsigned)bc);
        pmin[(size_t)k * NC + blockIdx.y] = best;
        pidx[(size_t)k * NC + blockIdx.y] = j;
    }
}

// ---------------------------------------------------------------------------
// finish_all: mismatch indicators + sup partials + mlp partials. 64 atomics.
// ---------------------------------------------------------------------------
__global__ __launch_bounds__(256) void finish_all(
    const int* __restrict__ im,
    const float* __restrict__ pm0, const int* __restrict__ pi0,
    const float* __restrict__ pm1, const int* __restrict__ pi1,
    const float* __restrict__ part_sup, const float* __restrict__ part_mlp,
    int K, float* __restrict__ out, float inv_k, float inv_n)
{
    const int gid = blockIdx.x * 256 + threadIdx.x;
    const int stride = gridDim.x * 256;
    float local = 0.f;

    for (int p = gid; p < 2 * K; p += stride) {
        const int dir = (p >= K);
        const int kk = dir ? p - K : p;
        const float* pm = dir ? pm1 : pm0;
        const int*   pi = dir ? pi1 : pi0;
        float best = __builtin_inff();
        int bi = 0x7fffffff;
        #pragma unroll
        for (int c = 0; c < NC; c++) {
            const float v = pm[(size_t)kk * NC + c];
            const int  ii = pi[(size_t)kk * NC + c];
            if (v < best || (v == best && ii < bi)) { best = v; bi = ii; }
        }
        if (bi != im[2 * kk + dir]) local += inv_k;
    }
    for (int i = gid; i < NB_SUP; i += stride) local += part_sup[i] * inv_k;
    for (int i = gid; i < NB_MLP; i += stride) local += part_mlp[i] * inv_n;

    #pragma unroll
    for (int o = 32; o > 0; o >>= 1) local += __shfl_down(local, o);
    __shared__ float wsum[4];
    if ((threadIdx.x & 63) == 0) wsum[threadIdx.x >> 6] = local;
    __syncthreads();
    if (threadIdx.x == 0) {
        const float t = wsum[0] + wsum[1] + wsum[2] + wsum[3];
        if (t != 0.f) atomicAdd(out, t);
    }
}

// ---------------------------------------------------------------------------
extern "C" void kernel_launch(void* const* d_in, const int* in_sizes, int n_in,
                              void* d_out, int out_size, void* d_ws, size_t ws_size,
                              hipStream_t stream)
{
    const float* xw    = (const float*)d_in[0];
    const float* yw    = (const float*)d_in[1];
    const float* fx_w1 = (const float*)d_in[2];
    const float* fx_b1 = (const float*)d_in[3];
    const float* fx_w2 = (const float*)d_in[4];
    const float* fx_b2 = (const float*)d_in[5];
    const float* gy_w1 = (const float*)d_in[6];
    const float* gy_b1 = (const float*)d_in[7];
    const float* gy_w2 = (const float*)d_in[8];
    const float* gy_b2 = (const float*)d_in[9];
    const int*   imap  = (const int*)d_in[10];
    float* out = (float*)d_out;
    float* ws  = (float*)d_ws;

    constexpr int N = NPTS, K = KPAIR;

    float* xm      = ws;                           // N*120
    float* ym      = xm + (size_t)N * 120;         // N*100
    float* tn_y    = ym + (size_t)N * 100;         // NPAD
    float* tn_x    = tn_y + NPAD;                  // NPAD
    float* pmin_fx = tn_x + NPAD;                  // K*NC
    int*   pidx_fx = (int*)(pmin_fx + (size_t)K * NC);
    float* pmin_gy = (float*)(pidx_fx + (size_t)K * NC);
    int*   pidx_gy = (int*)(pmin_gy + (size_t)K * NC);
    unsigned char* ybf8 = (unsigned char*)(pidx_gy + (size_t)K * NC); // NPAD*128 B
    unsigned char* xbf8 = ybf8 + (size_t)NPAD * 128;                  // NPAD*128 B
    unsigned char* axf8 = xbf8 + (size_t)NPAD * 128;                  // K*128 B
    unsigned char* ayf8 = axf8 + (size_t)K * 128;
    unsigned short* wp_fx1 = (unsigned short*)(ayf8 + (size_t)K * 128); // 28*512
    unsigned short* wp_fx2 = wp_fx1 + 28 * 512;      // 32*512
    unsigned short* wp_gy1 = wp_fx2 + 32 * 512;      // 28*512
    unsigned short* wp_gy2 = wp_gy1 + 28 * 512;      // 28*512
    float* part_sup = (float*)(wp_gy2 + 28 * 512);   // NB_SUP
    float* part_mlp = part_sup + NB_SUP;             // NB_MLP

    hipMemsetAsync(d_out, 0, sizeof(float), stream);

    prep_kernel<<<PREP_B + 29, 256, 0, stream>>>(
        yw, ybf8, tn_y, xw, xbf8, tn_x,
        fx_w1, wp_fx1, fx_w2, wp_fx2, gy_w1, wp_gy1, gy_w2, wp_gy2, N);

    mlp_both<<<2 * GM, 128, 0, stream>>>(
        xw, yw,
        wp_fx1, fx_b1, wp_fx2, fx_b2, wp_gy1, gy_b1, wp_gy2, gy_b2,
        xm, ym, part_mlp, N);

    sup_gather<<<NB_SUP, 256, 0, stream>>>(xm, ym, xw, yw, imap, K, part_sup, axf8, ayf8);

    dim3 g1((K + 255) / 256, NC, 2);
    nn_mfma<<<g1, 256, 0, stream>>>(axf8, ybf8, tn_y, pmin_fx, pidx_fx,
                                    ayf8, xbf8, tn_x, pmin_gy, pidx_gy, K);

    finish_all<<<64, 256, 0, stream>>>(
        imap, pmin_fx, pidx_fx, pmin_gy, pidx_gy, part_sup, part_mlp,
        K, out, 1.f / K, 1.f / N);
}